// Round 1
// baseline (2939.797 us; speedup 1.0000x reference)
//
#include <hip/hip_runtime.h>

#define TPB 512

// ---------------- block-wide reductions (512 threads = 8 waves) ----------------
__device__ __forceinline__ float blk_reduce_max(float v, float* sred, int tid) {
#pragma unroll
  for (int o = 32; o > 0; o >>= 1) v = fmaxf(v, __shfl_down(v, o));
  if ((tid & 63) == 0) sred[tid >> 6] = v;
  __syncthreads();
  if (tid == 0) {
    float m = sred[0];
#pragma unroll
    for (int w = 1; w < TPB / 64; ++w) m = fmaxf(m, sred[w]);
    sred[0] = m;
  }
  __syncthreads();
  const float r = sred[0];
  __syncthreads();
  return r;
}

__device__ __forceinline__ float blk_reduce_sum(float v, float* sred, int tid) {
#pragma unroll
  for (int o = 32; o > 0; o >>= 1) v += __shfl_down(v, o);
  if ((tid & 63) == 0) sred[tid >> 6] = v;
  __syncthreads();
  if (tid == 0) {
    float m = sred[0];
#pragma unroll
    for (int w = 1; w < TPB / 64; ++w) m += sred[w];
    sred[0] = m;
  }
  __syncthreads();
  const float r = sred[0];
  __syncthreads();
  return r;
}

// ---------------- Kernel A: exact Riccati iterations until convergence ----------------
// n=128 states, m=64 controls, d=192. Single workgroup, state in LDS.
__global__ __launch_bounds__(TPB) void lqr_iter(
    const float* __restrict__ Fg,   // [128][192]
    const float* __restrict__ fg,   // [128]
    const float* __restrict__ Cg,   // [192][192]
    const float* __restrict__ cg,   // [192]
    float* __restrict__ out,        // K|k|V|v|const stacks, time-reversed
    float* __restrict__ ws, int T)
{
  const int tid = threadIdx.x;

  __shared__ __align__(16) float pool[39584];   // 158,336 B
  float* const sV   = pool;                      // [128][132]  V state (padded)
  float* const sQXU = pool + 16896;              // [128][68]   Qxu (row i, col u)
  float* const sQUU = pool + 25600;              // [64][68]    Quu
  float* const sTMP = pool + 29952;              // H panel [128][36] / Newton T1 [64][68]
  float* const sX   = pool + 34560;              // [64][68]    X ~= inv(Quu), persists (warm start)
  float* const sWT  = sQUU;                      // overlay [128][68] = W^T  (QUU+TMP = 8960 floats >= 8704)
  float* const sf   = pool + 38912;              // [128]
  float* const sv   = sf + 128;                  // [128]
  float* const sz   = sv + 128;                  // [128]  V@f, then z = V@f + v
  float* const sq   = sz + 128;                  // [192]  q
  float* const sk   = sq + 192;                  // [64]   k
  float* const sred = sk + 64;                   // [16]
  float* const sS   = sred + 16;                 // [16]   sS[0]=const, sS[1]=cstep

  const size_t okOff = (size_t)T * 8192;
  const size_t oVOff = okOff + (size_t)T * 64;
  const size_t ovOff = oVOff + (size_t)T * 16384;
  const size_t ocOff = ovOff + (size_t)T * 128;

  // ---- init: V0 = C[:128,:128], v0 = c[:128], X = I, const = 0
  for (int idx = tid; idx < 128 * 128; idx += TPB) {
    const int i = idx >> 7, j = idx & 127;
    sV[i * 132 + j] = Cg[i * 192 + j];
  }
  if (tid < 128) { sf[tid] = fg[tid]; sv[tid] = cg[tid]; }
  for (int idx = tid; idx < 64 * 68; idx += TPB) {
    const int a = idx / 68, b = idx - a * 68;
    sX[idx] = (a == b) ? 1.f : 0.f;
  }
  if (tid == 0) { sS[0] = 0.f; sS[1] = 0.f; }
  __syncthreads();

  int Sdone = T;

  for (int it = 0; it < T; ++it) {
    const int rrow = T - 1 - it;
    float* const outVrow = out + oVOff + (size_t)rrow * 16384;  // also used as Qxx scratch

    // ================= A: vectors: wVf = V@f, fVf, fv, z, q = c + F^T z
    float wv = 0.f;
    if (tid < 128) {
#pragma unroll 4
      for (int m = 0; m < 128; ++m) wv = fmaf(sV[tid * 132 + m], sf[m], wv);
    }
    float p1 = 0.f, p2 = 0.f;
    if (tid < 128) { p1 = sf[tid] * wv; p2 = sf[tid] * sv[tid]; sz[tid] = wv + sv[tid]; }
    const float fVf = blk_reduce_sum(p1, sred, tid);
    const float fv  = blk_reduce_sum(p2, sred, tid);
    if (tid < 192) {
      float qa = cg[tid];
#pragma unroll 4
      for (int k = 0; k < 128; ++k) qa = fmaf(Fg[k * 192 + tid], sz[k], qa);
      sq[tid] = qa;
    }
    __syncthreads();

    // ================= B: Q = C + F^T V F  via H = V@F panels of 32 cols
    for (int p = 0; p < 6; ++p) {
      const int j0 = p * 32;
      {  // H panel: H[k][jj] = sum_m V[k][m] * F[m][j0+jj]   -> sTMP [128][36]
        const int jj = tid & 31, kg = tid >> 5;   // kg 0..15, 8 rows each
        float h[8] = {0, 0, 0, 0, 0, 0, 0, 0};
        for (int m4 = 0; m4 < 32; ++m4) {
          const float b0 = Fg[(m4 * 4 + 0) * 192 + j0 + jj];
          const float b1 = Fg[(m4 * 4 + 1) * 192 + j0 + jj];
          const float b2 = Fg[(m4 * 4 + 2) * 192 + j0 + jj];
          const float b3 = Fg[(m4 * 4 + 3) * 192 + j0 + jj];
#pragma unroll
          for (int r = 0; r < 8; ++r) {
            const float4 a = *(const float4*)&sV[(kg * 8 + r) * 132 + m4 * 4];
            h[r] = fmaf(a.x, b0, fmaf(a.y, b1, fmaf(a.z, b2, fmaf(a.w, b3, h[r]))));
          }
        }
#pragma unroll
        for (int r = 0; r < 8; ++r) sTMP[(kg * 8 + r) * 36 + jj] = h[r];
        __syncthreads();
      }
      if (p < 4) {  // x-columns: rows i in [0,192): Qxx -> global scratch, Qux -> sQXU
        const int jj = tid & 31, ig = tid >> 5, i0 = ig * 12, j = j0 + jj;
        float qa[12] = {0, 0, 0, 0, 0, 0, 0, 0, 0, 0, 0, 0};
#pragma unroll 2
        for (int k = 0; k < 128; ++k) {
          const float hb = sTMP[k * 36 + jj];
          const float4 a0 = *(const float4*)&Fg[k * 192 + i0];
          const float4 a1 = *(const float4*)&Fg[k * 192 + i0 + 4];
          const float4 a2 = *(const float4*)&Fg[k * 192 + i0 + 8];
          const float av[12] = {a0.x, a0.y, a0.z, a0.w, a1.x, a1.y, a1.z, a1.w,
                                a2.x, a2.y, a2.z, a2.w};
#pragma unroll
          for (int r = 0; r < 12; ++r) qa[r] = fmaf(av[r], hb, qa[r]);
        }
#pragma unroll
        for (int r = 0; r < 12; ++r) {
          const int i = i0 + r;
          const float val = Cg[i * 192 + j] + qa[r];
          if (i < 128) outVrow[i * 128 + j] = val;        // Qxx scratch
          else         sQXU[j * 68 + (i - 128)] = val;    // Qxu[j][u] (Q symmetric)
        }
        __syncthreads();
      } else {      // u-columns: rows i in [128,192): Quu -> sQUU
        const int jj = tid & 31, ug = tid >> 5, u0 = ug * 4;
        float qa[4] = {0, 0, 0, 0};
#pragma unroll 2
        for (int k = 0; k < 128; ++k) {
          const float hb = sTMP[k * 36 + jj];
          const float4 a0 = *(const float4*)&Fg[k * 192 + 128 + u0];
          qa[0] = fmaf(a0.x, hb, qa[0]); qa[1] = fmaf(a0.y, hb, qa[1]);
          qa[2] = fmaf(a0.z, hb, qa[2]); qa[3] = fmaf(a0.w, hb, qa[3]);
        }
#pragma unroll
        for (int r = 0; r < 4; ++r)
          sQUU[(u0 + r) * 68 + (j0 - 128 + jj)] =
              Cg[(128 + u0 + r) * 192 + j0 + jj] + qa[r];
        __syncthreads();
      }
    }

    // ================= C: Newton iteration for X ~= inv(Quu), warm-started
    {
      const int bg = tid & 7, aN = tid >> 3;   // aN row 0..63, 8 cols each
      bool did_reset = false;
      float prev = 1e30f;
      for (int ns = 0; ns < 40; ++ns) {
        float t1[8] = {0, 0, 0, 0, 0, 0, 0, 0};
        for (int u = 0; u < 64; ++u) {
          const float qa = sQUU[aN * 68 + u];
          const float4 x0 = *(const float4*)&sX[u * 68 + bg * 8];
          const float4 x1 = *(const float4*)&sX[u * 68 + bg * 8 + 4];
          const float xv[8] = {x0.x, x0.y, x0.z, x0.w, x1.x, x1.y, x1.z, x1.w};
#pragma unroll
          for (int e = 0; e < 8; ++e) t1[e] = fmaf(qa, xv[e], t1[e]);
        }
        float rs_ = 0.f;
#pragma unroll
        for (int e = 0; e < 8; ++e) {
          const int b = bg * 8 + e;
          rs_ += fabsf(t1[e] - ((aN == b) ? 1.f : 0.f));
        }
        rs_ += __shfl_xor(rs_, 1); rs_ += __shfl_xor(rs_, 2); rs_ += __shfl_xor(rs_, 4);
        *(float4*)&sTMP[aN * 68 + bg * 8]     = make_float4(t1[0], t1[1], t1[2], t1[3]);
        *(float4*)&sTMP[aN * 68 + bg * 8 + 4] = make_float4(t1[4], t1[5], t1[6], t1[7]);
        const float rinf = blk_reduce_max(rs_, sred, tid);  // barriers also publish sTMP
        if (rinf < 3e-6f) break;
        const bool bad = (!did_reset) && (rinf >= 0.9f || rinf >= prev || !(rinf < 1e30f));
        prev = rinf;
        if (bad) {   // guaranteed-convergent restart: X = I / ||Quu||_inf
          did_reset = true; prev = 1e30f;
          float rsum = 0.f;
          if (tid < 64) {
            for (int u = 0; u < 64; ++u) rsum += fabsf(sQUU[tid * 68 + u]);
          }
          const float s = blk_reduce_max(rsum, sred, tid);
          const float invs = 1.f / s;
#pragma unroll
          for (int e = 0; e < 8; ++e) {
            const int b = bg * 8 + e;
            sX[aN * 68 + b] = (aN == b) ? invs : 0.f;
          }
          __syncthreads();
          continue;
        }
        // Xn = 2X - X @ T1  (into registers, then write back)
        float xn[8] = {0, 0, 0, 0, 0, 0, 0, 0};
        for (int u = 0; u < 64; ++u) {
          const float xa = sX[aN * 68 + u];
          const float4 t0 = *(const float4*)&sTMP[u * 68 + bg * 8];
          const float4 t4 = *(const float4*)&sTMP[u * 68 + bg * 8 + 4];
          const float tv[8] = {t0.x, t0.y, t0.z, t0.w, t4.x, t4.y, t4.z, t4.w};
#pragma unroll
          for (int e = 0; e < 8; ++e) xn[e] = fmaf(xa, tv[e], xn[e]);
        }
        const float4 xo0 = *(const float4*)&sX[aN * 68 + bg * 8];
        const float4 xo4 = *(const float4*)&sX[aN * 68 + bg * 8 + 4];
        __syncthreads();
        *(float4*)&sX[aN * 68 + bg * 8] =
            make_float4(2.f * xo0.x - xn[0], 2.f * xo0.y - xn[1],
                        2.f * xo0.z - xn[2], 2.f * xo0.w - xn[3]);
        *(float4*)&sX[aN * 68 + bg * 8 + 4] =
            make_float4(2.f * xo4.x - xn[4], 2.f * xo4.y - xn[5],
                        2.f * xo4.z - xn[6], 2.f * xo4.w - xn[7]);
        __syncthreads();
      }
    }

    // ================= D: k = -X@qu, cstep, const
    float kQk_p = 0.f, kqu_p = 0.f;
    if (tid < 64) {
      float ka = 0.f;
      for (int u = 0; u < 64; ++u) ka = fmaf(sX[tid * 68 + u], sq[128 + u], ka);
      ka = -ka;
      sk[tid] = ka;
      out[okOff + (size_t)rrow * 64 + tid] = ka;
    }
    __syncthreads();
    if (tid < 64) {
      float ta = 0.f;
      for (int u = 0; u < 64; ++u) ta = fmaf(sQUU[tid * 68 + u], sk[u], ta);
      kQk_p = sk[tid] * ta;
      kqu_p = sk[tid] * sq[128 + tid];
    }
    const float kQk = blk_reduce_sum(kQk_p, sred, tid);
    const float kqu = blk_reduce_sum(kqu_p, sred, tid);
    if (tid == 0) {
      const float cstep_ = 0.5f * kQk + kqu + 0.5f * fVf + fv;
      const float cnew = sS[0] + cstep_;
      sS[0] = cnew; sS[1] = cstep_;
      out[ocOff + rrow] = cnew;
    }
    __syncthreads();   // Quu dead; WT may overlay it now

    // ================= E: W^T[j][a] = sum_u Qxu[j][u]*X[u][a];  K = -W
    {
      const int ag = tid & 3, j = tid >> 2, a0 = ag * 16;
      float w[16] = {0, 0, 0, 0, 0, 0, 0, 0, 0, 0, 0, 0, 0, 0, 0, 0};
      for (int u = 0; u < 64; ++u) {
        const float qx_ = sQXU[j * 68 + u];
        const float4 x0 = *(const float4*)&sX[u * 68 + a0];
        const float4 x1 = *(const float4*)&sX[u * 68 + a0 + 4];
        const float4 x2 = *(const float4*)&sX[u * 68 + a0 + 8];
        const float4 x3 = *(const float4*)&sX[u * 68 + a0 + 12];
        const float xv[16] = {x0.x, x0.y, x0.z, x0.w, x1.x, x1.y, x1.z, x1.w,
                              x2.x, x2.y, x2.z, x2.w, x3.x, x3.y, x3.z, x3.w};
#pragma unroll
        for (int e = 0; e < 16; ++e) w[e] = fmaf(qx_, xv[e], w[e]);
      }
      *(float4*)&sWT[j * 68 + a0]      = make_float4(w[0], w[1], w[2], w[3]);
      *(float4*)&sWT[j * 68 + a0 + 4]  = make_float4(w[4], w[5], w[6], w[7]);
      *(float4*)&sWT[j * 68 + a0 + 8]  = make_float4(w[8], w[9], w[10], w[11]);
      *(float4*)&sWT[j * 68 + a0 + 12] = make_float4(w[12], w[13], w[14], w[15]);
      float* const outK = out + (size_t)rrow * 8192;
#pragma unroll
      for (int e = 0; e < 16; ++e) outK[(a0 + e) * 128 + j] = -w[e];
      __syncthreads();
    }

    // ================= F: Vn = Qxx - Qxu@W ; vn = qx + Qxu@k ; convergence
    {
      const int jg = tid & 3, i = tid >> 2;
      float acc[32];
#pragma unroll
      for (int r = 0; r < 32; ++r) acc[r] = 0.f;
      for (int u4 = 0; u4 < 16; ++u4) {
        const float4 qa = *(const float4*)&sQXU[i * 68 + u4 * 4];
#pragma unroll
        for (int r = 0; r < 32; ++r) {
          const float4 wb = *(const float4*)&sWT[(jg + 4 * r) * 68 + u4 * 4];
          acc[r] += qa.x * wb.x + qa.y * wb.y + qa.z * wb.z + qa.w * wb.w;
        }
      }
      float dmax = 0.f, vmax = 0.f;
#pragma unroll
      for (int r = 0; r < 32; ++r) {
        const int j = jg + 4 * r;
        const float vn_ = outVrow[i * 128 + j] - acc[r];
        dmax = fmaxf(dmax, fabsf(vn_ - sV[i * 132 + j]));
        vmax = fmaxf(vmax, fabsf(vn_));
        sV[i * 132 + j] = vn_;
        outVrow[i * 128 + j] = vn_;
      }
      float dv_p = 0.f, mv_p = 0.f;
      if (tid < 128) {
        float va = sq[tid];
        for (int u = 0; u < 64; ++u) va = fmaf(sQXU[tid * 68 + u], sk[u], va);
        dv_p = fabsf(va - sv[tid]); mv_p = fabsf(va);
        sv[tid] = va;
        out[ovOff + (size_t)rrow * 128 + tid] = va;
      }
      const float dV = blk_reduce_max(dmax, sred, tid);
      const float mV = blk_reduce_max(vmax, sred, tid);
      const float dv = blk_reduce_max(dv_p, sred, tid);
      const float mv = blk_reduce_max(mv_p, sred, tid);
      if (dV <= 1e-4f * mV && dv <= 3e-4f * fmaxf(1.f, mv)) { Sdone = it + 1; break; }
    }
  }

  if (tid == 0) {
    ((int*)ws)[0] = Sdone;
    ws[1] = sS[1];   // converged cstep
    ws[2] = sS[0];   // const at iteration Sdone-1
  }
}

// ---------------- Kernel B: replicate converged rows + affine const ----------------
__global__ __launch_bounds__(256) void lqr_fill(
    const float* __restrict__ ws, float* __restrict__ out, int T)
{
  const int S = ((const int*)ws)[0];
  const float cstep = ws[1];
  const float cbase = ws[2];
  const int r = blockIdx.x;
  const int it = T - 1 - r;          // scan-iteration index of this output row
  if (it < S) return;                // exact rows already written by kernel A
  const int rs = T - S;              // source row = iteration S-1
  const int tid = threadIdx.x;
  const size_t okOff = (size_t)T * 8192;
  const size_t oVOff = okOff + (size_t)T * 64;
  const size_t ovOff = oVOff + (size_t)T * 16384;
  const size_t ocOff = ovOff + (size_t)T * 128;

  const float4* __restrict__ sK = (const float4*)(out + (size_t)rs * 8192);
  float4* __restrict__ dK = (float4*)(out + (size_t)r * 8192);
  for (int i = tid; i < 2048; i += 256) dK[i] = sK[i];
  const float4* __restrict__ sVr = (const float4*)(out + oVOff + (size_t)rs * 16384);
  float4* __restrict__ dV = (float4*)(out + oVOff + (size_t)r * 16384);
  for (int i = tid; i < 4096; i += 256) dV[i] = sVr[i];
  if (tid < 16)
    ((float4*)(out + okOff + (size_t)r * 64))[tid] =
        ((const float4*)(out + okOff + (size_t)rs * 64))[tid];
  if (tid >= 32 && tid < 64) {
    const int q = tid - 32;
    ((float4*)(out + ovOff + (size_t)r * 128))[q] =
        ((const float4*)(out + ovOff + (size_t)rs * 128))[q];
  }
  if (tid == 0) out[ocOff + r] = cbase + (float)(it - (S - 1)) * cstep;
}

extern "C" void kernel_launch(void* const* d_in, const int* in_sizes, int n_in,
                              void* d_out, int out_size, void* d_ws, size_t ws_size,
                              hipStream_t stream) {
  const float* F = (const float*)d_in[0];
  const float* f = (const float*)d_in[1];
  const float* C = (const float*)d_in[2];
  const float* c = (const float*)d_in[3];
  // T derived from out_size: per-step outputs = 64*128 + 64 + 128*128 + 128 + 1 = 24769
  const int T = out_size / 24769;
  float* out = (float*)d_out;
  float* ws = (float*)d_ws;

  hipLaunchKernelGGL(lqr_iter, dim3(1), dim3(TPB), 0, stream, F, f, C, c, out, ws, T);
  hipLaunchKernelGGL(lqr_fill, dim3(T), dim3(256), 0, stream, ws, out, T);
}

// Round 4
// 2512.972 us; speedup vs baseline: 1.1698x; 1.1698x over previous
//
#include <hip/hip_runtime.h>

#define TPB 512

// ---------------- block-wide reductions (512 threads = 8 waves) ----------------
__device__ __forceinline__ float blk_reduce_max(float v, float* sred, int tid) {
#pragma unroll
  for (int o = 32; o > 0; o >>= 1) v = fmaxf(v, __shfl_down(v, o));
  if ((tid & 63) == 0) sred[tid >> 6] = v;
  __syncthreads();
  if (tid == 0) {
    float m = sred[0];
#pragma unroll
    for (int w = 1; w < TPB / 64; ++w) m = fmaxf(m, sred[w]);
    sred[0] = m;
  }
  __syncthreads();
  const float r = sred[0];
  __syncthreads();
  return r;
}

__device__ __forceinline__ float blk_reduce_sum(float v, float* sred, int tid) {
#pragma unroll
  for (int o = 32; o > 0; o >>= 1) v += __shfl_down(v, o);
  if ((tid & 63) == 0) sred[tid >> 6] = v;
  __syncthreads();
  if (tid == 0) {
    float m = sred[0];
#pragma unroll
    for (int w = 1; w < TPB / 64; ++w) m += sred[w];
    sred[0] = m;
  }
  __syncthreads();
  const float r = sred[0];
  __syncthreads();
  return r;
}

__device__ __forceinline__ float dot_f4(const float* __restrict__ a,
                                        const float* __restrict__ b, int n4) {
  float acc = 0.f;
#pragma unroll 8
  for (int c = 0; c < n4; ++c) {
    const float4 x = ((const float4*)a)[c];
    const float4 y = ((const float4*)b)[c];
    acc = fmaf(x.x, y.x, fmaf(x.y, y.y, fmaf(x.z, y.z, fmaf(x.w, y.w, acc))));
  }
  return acc;
}

// ---------------- Kernel A: exact Riccati iterations until convergence ----------------
// n=128 states, m=64 controls, d=192. Single workgroup, state in LDS.
// Structure identical to the round-1 PASSING kernel; only the Newton inverse
// (adaptive exit instead of fixed 40 steps) and the stop criterion changed.
__global__ __launch_bounds__(TPB) void lqr_iter(
    const float* __restrict__ Fg,   // [128][192]
    const float* __restrict__ fg,   // [128]
    const float* __restrict__ Cg,   // [192][192]
    const float* __restrict__ cg,   // [192]
    float* __restrict__ out,        // K|k|V|v|const stacks, time-reversed
    float* __restrict__ ws, int T)
{
  const int tid = threadIdx.x;

  __shared__ __align__(16) float pool[39584];   // 158,336 B (round-1 proven)
  float* const sV   = pool;                      // [128][132]  V state (padded)
  float* const sQXU = pool + 16896;              // [128][68]   Qxu (row i, col u)
  float* const sQUU = pool + 25600;              // [64][68]    Quu
  float* const sTMP = pool + 29952;              // H panel [128][36] / Newton T1 [64][68]
  float* const sX   = pool + 34560;              // [64][68]    X ~= inv(Quu), warm-started
  float* const sWT  = sQUU;                      // overlay [128][68] = W^T
  float* const sf   = pool + 38912;              // [128]
  float* const sv   = sf + 128;                  // [128]
  float* const sz   = sv + 128;                  // [128]
  float* const sq   = sz + 128;                  // [192]
  float* const sk   = sq + 192;                  // [64]
  float* const sred = sk + 64;                   // [16]
  float* const sS   = sred + 16;                 // [0]=const,[1]=cstep,[3]=|dcstep|

  const size_t okOff = (size_t)T * 8192;
  const size_t oVOff = okOff + (size_t)T * 64;
  const size_t ovOff = oVOff + (size_t)T * 16384;
  const size_t ocOff = ovOff + (size_t)T * 128;

  // ---- init: V0 = C[:128,:128], v0 = c[:128], X = I, const = 0
  for (int idx = tid; idx < 128 * 128; idx += TPB) {
    const int i = idx >> 7, j = idx & 127;
    sV[i * 132 + j] = Cg[i * 192 + j];
  }
  if (tid < 128) { sf[tid] = fg[tid]; sv[tid] = cg[tid]; }
  for (int idx = tid; idx < 64 * 68; idx += TPB) {
    const int a = idx / 68, b = idx - a * 68;
    sX[idx] = (a == b) ? 1.f : 0.f;
  }
  if (tid == 0) { sS[0] = 0.f; sS[1] = 0.f; sS[3] = 1e30f; }
  __syncthreads();

  int Sdone = T;

  for (int it = 0; it < T; ++it) {
    const int rrow = T - 1 - it;
    float* const outVrow = out + oVOff + (size_t)rrow * 16384;  // Qxx scratch

    // ================= A: wVf = V@f, fVf, fv, z, q = c + F^T z
    float wv = 0.f;
    if (tid < 128) wv = dot_f4(&sV[tid * 132], sf, 32);
    float p1 = 0.f, p2 = 0.f;
    if (tid < 128) { p1 = sf[tid] * wv; p2 = sf[tid] * sv[tid]; sz[tid] = wv + sv[tid]; }
    const float fVf = blk_reduce_sum(p1, sred, tid);
    const float fv  = blk_reduce_sum(p2, sred, tid);
    if (tid < 192) {
      float qa = cg[tid];
#pragma unroll 4
      for (int k = 0; k < 128; ++k) qa = fmaf(Fg[k * 192 + tid], sz[k], qa);
      sq[tid] = qa;
    }
    __syncthreads();

    // ================= B: Q = C + F^T V F via H = V@F panels of 32 cols
    for (int p = 0; p < 6; ++p) {
      const int j0 = p * 32;
      {  // H panel: H[k][jj] = sum_m V[k][m] * F[m][j0+jj] -> sTMP [128][36]
        const int jj = tid & 31, kg = tid >> 5;
        float h[8] = {0, 0, 0, 0, 0, 0, 0, 0};
        for (int m4 = 0; m4 < 32; ++m4) {
          const float b0 = Fg[(m4 * 4 + 0) * 192 + j0 + jj];
          const float b1 = Fg[(m4 * 4 + 1) * 192 + j0 + jj];
          const float b2 = Fg[(m4 * 4 + 2) * 192 + j0 + jj];
          const float b3 = Fg[(m4 * 4 + 3) * 192 + j0 + jj];
#pragma unroll
          for (int r = 0; r < 8; ++r) {
            const float4 a = *(const float4*)&sV[(kg * 8 + r) * 132 + m4 * 4];
            h[r] = fmaf(a.x, b0, fmaf(a.y, b1, fmaf(a.z, b2, fmaf(a.w, b3, h[r]))));
          }
        }
#pragma unroll
        for (int r = 0; r < 8; ++r) sTMP[(kg * 8 + r) * 36 + jj] = h[r];
        __syncthreads();
      }
      if (p < 4) {  // x-cols: Qxx -> global scratch, Qux -> sQXU
        const int jj = tid & 31, ig = tid >> 5, i0 = ig * 12, j = j0 + jj;
        float qa[12] = {0, 0, 0, 0, 0, 0, 0, 0, 0, 0, 0, 0};
#pragma unroll 2
        for (int k = 0; k < 128; ++k) {
          const float hb = sTMP[k * 36 + jj];
          const float4 a0 = *(const float4*)&Fg[k * 192 + i0];
          const float4 a1 = *(const float4*)&Fg[k * 192 + i0 + 4];
          const float4 a2 = *(const float4*)&Fg[k * 192 + i0 + 8];
          const float av[12] = {a0.x, a0.y, a0.z, a0.w, a1.x, a1.y, a1.z, a1.w,
                                a2.x, a2.y, a2.z, a2.w};
#pragma unroll
          for (int r = 0; r < 12; ++r) qa[r] = fmaf(av[r], hb, qa[r]);
        }
#pragma unroll
        for (int r = 0; r < 12; ++r) {
          const int i = i0 + r;
          const float val = Cg[i * 192 + j] + qa[r];
          if (i < 128) outVrow[i * 128 + j] = val;
          else         sQXU[j * 68 + (i - 128)] = val;
        }
        __syncthreads();
      } else {      // u-cols: Quu -> sQUU
        const int jj = tid & 31, ug = tid >> 5, u0 = ug * 4;
        float qa[4] = {0, 0, 0, 0};
#pragma unroll 2
        for (int k = 0; k < 128; ++k) {
          const float hb = sTMP[k * 36 + jj];
          const float4 a0 = *(const float4*)&Fg[k * 192 + 128 + u0];
          qa[0] = fmaf(a0.x, hb, qa[0]); qa[1] = fmaf(a0.y, hb, qa[1]);
          qa[2] = fmaf(a0.z, hb, qa[2]); qa[3] = fmaf(a0.w, hb, qa[3]);
        }
#pragma unroll
        for (int r = 0; r < 4; ++r)
          sQUU[(u0 + r) * 68 + (j0 - 128 + jj)] =
              Cg[(128 + u0 + r) * 192 + j0 + jj] + qa[r];
        __syncthreads();
      }
    }

    // ================= C: Newton for X ~= inv(Quu), adaptive, warm-started
    {
      const int bg = tid & 7, aN = tid >> 3, b0 = bg * 8;
      int phase = 0;                 // 0 = warm start, 1 = after clean reset
      float prev = 1e30f, rmax = 1e30f;
      for (int ns = 0; ns < 44; ++ns) {
        // T1 = Quu @ X ; exact inf-norm residual (8 threads own one row)
        float t1[8] = {0, 0, 0, 0, 0, 0, 0, 0};
        for (int u = 0; u < 64; ++u) {
          const float qa = sQUU[aN * 68 + u];
          const float4 x0 = *(const float4*)&sX[u * 68 + b0];
          const float4 x1 = *(const float4*)&sX[u * 68 + b0 + 4];
          t1[0] = fmaf(qa, x0.x, t1[0]); t1[1] = fmaf(qa, x0.y, t1[1]);
          t1[2] = fmaf(qa, x0.z, t1[2]); t1[3] = fmaf(qa, x0.w, t1[3]);
          t1[4] = fmaf(qa, x1.x, t1[4]); t1[5] = fmaf(qa, x1.y, t1[5]);
          t1[6] = fmaf(qa, x1.z, t1[6]); t1[7] = fmaf(qa, x1.w, t1[7]);
        }
        float rs_ = 0.f;
#pragma unroll
        for (int e = 0; e < 8; ++e)
          rs_ += fabsf(t1[e] - ((aN == b0 + e) ? 1.f : 0.f));
        rs_ += __shfl_xor(rs_, 1); rs_ += __shfl_xor(rs_, 2); rs_ += __shfl_xor(rs_, 4);
        if (!(rs_ == rs_)) rs_ = 1e30f;   // NaN poison (fmaxf filters NaN)
        *(float4*)&sTMP[aN * 68 + b0]     = make_float4(t1[0], t1[1], t1[2], t1[3]);
        *(float4*)&sTMP[aN * 68 + b0 + 4] = make_float4(t1[4], t1[5], t1[6], t1[7]);
        rmax = blk_reduce_max(rs_, sred, tid);  // barriers also publish sTMP
        if (rmax < 1.5e-4f) break;
        const bool doReset = (phase == 0) && (!(rmax < 0.9f * prev) || rmax > 2.f);
        if (!doReset && phase == 1 && !(rmax < 0.97f * prev) && rmax < 1e-2f)
          break;                           // fp32 residual floor plateau
        prev = rmax;
        if (doReset) {                     // X = I / ||Quu||_inf (SPD-safe init)
          phase = 1; prev = 1e30f;
          float rsum = 0.f;
          if (tid < 64)
            for (int u = 0; u < 64; ++u) rsum += fabsf(sQUU[tid * 68 + u]);
          const float s = blk_reduce_max(rsum, sred, tid);
          const float invs = 1.f / s;
          for (int idx = tid; idx < 64 * 68; idx += TPB) {
            const int a2 = idx / 68, b2 = idx - a2 * 68;
            sX[idx] = (a2 == b2) ? invs : 0.f;
          }
          __syncthreads();
          continue;
        }
        // Xn = 2X - X @ T1
        float xn[8] = {0, 0, 0, 0, 0, 0, 0, 0};
        for (int u = 0; u < 64; ++u) {
          const float xa = sX[aN * 68 + u];
          const float4 t0 = *(const float4*)&sTMP[u * 68 + b0];
          const float4 t4 = *(const float4*)&sTMP[u * 68 + b0 + 4];
          xn[0] = fmaf(xa, t0.x, xn[0]); xn[1] = fmaf(xa, t0.y, xn[1]);
          xn[2] = fmaf(xa, t0.z, xn[2]); xn[3] = fmaf(xa, t0.w, xn[3]);
          xn[4] = fmaf(xa, t4.x, xn[4]); xn[5] = fmaf(xa, t4.y, xn[5]);
          xn[6] = fmaf(xa, t4.z, xn[6]); xn[7] = fmaf(xa, t4.w, xn[7]);
        }
        const float4 xo0 = *(const float4*)&sX[aN * 68 + b0];
        const float4 xo4 = *(const float4*)&sX[aN * 68 + b0 + 4];
        __syncthreads();
        *(float4*)&sX[aN * 68 + b0] =
            make_float4(2.f * xo0.x - xn[0], 2.f * xo0.y - xn[1],
                        2.f * xo0.z - xn[2], 2.f * xo0.w - xn[3]);
        *(float4*)&sX[aN * 68 + b0 + 4] =
            make_float4(2.f * xo4.x - xn[4], 2.f * xo4.y - xn[5],
                        2.f * xo4.z - xn[6], 2.f * xo4.w - xn[7]);
        __syncthreads();
      }
      if (!(rmax < 5e-2f)) {   // cold safety rebuild: guaranteed-convergent for SPD
        float rsum = 0.f;
        if (tid < 64)
          for (int u = 0; u < 64; ++u) rsum += fabsf(sQUU[tid * 68 + u]);
        const float s = blk_reduce_max(rsum, sred, tid);
        const float invs = 1.f / s;
        for (int idx = tid; idx < 64 * 68; idx += TPB) {
          const int a2 = idx / 68, b2 = idx - a2 * 68;
          sX[idx] = (a2 == b2) ? invs : 0.f;
        }
        __syncthreads();
        for (int ns = 0; ns < 18; ++ns) {
          float t1[8] = {0, 0, 0, 0, 0, 0, 0, 0};
          for (int u = 0; u < 64; ++u) {
            const float qa = sQUU[aN * 68 + u];
            const float4 x0 = *(const float4*)&sX[u * 68 + b0];
            const float4 x1 = *(const float4*)&sX[u * 68 + b0 + 4];
            t1[0] = fmaf(qa, x0.x, t1[0]); t1[1] = fmaf(qa, x0.y, t1[1]);
            t1[2] = fmaf(qa, x0.z, t1[2]); t1[3] = fmaf(qa, x0.w, t1[3]);
            t1[4] = fmaf(qa, x1.x, t1[4]); t1[5] = fmaf(qa, x1.y, t1[5]);
            t1[6] = fmaf(qa, x1.z, t1[6]); t1[7] = fmaf(qa, x1.w, t1[7]);
          }
          *(float4*)&sTMP[aN * 68 + b0]     = make_float4(t1[0], t1[1], t1[2], t1[3]);
          *(float4*)&sTMP[aN * 68 + b0 + 4] = make_float4(t1[4], t1[5], t1[6], t1[7]);
          __syncthreads();
          float xn[8] = {0, 0, 0, 0, 0, 0, 0, 0};
          for (int u = 0; u < 64; ++u) {
            const float xa = sX[aN * 68 + u];
            const float4 t0 = *(const float4*)&sTMP[u * 68 + b0];
            const float4 t4 = *(const float4*)&sTMP[u * 68 + b0 + 4];
            xn[0] = fmaf(xa, t0.x, xn[0]); xn[1] = fmaf(xa, t0.y, xn[1]);
            xn[2] = fmaf(xa, t0.z, xn[2]); xn[3] = fmaf(xa, t0.w, xn[3]);
            xn[4] = fmaf(xa, t4.x, xn[4]); xn[5] = fmaf(xa, t4.y, xn[5]);
            xn[6] = fmaf(xa, t4.z, xn[6]); xn[7] = fmaf(xa, t4.w, xn[7]);
          }
          const float4 xo0 = *(const float4*)&sX[aN * 68 + b0];
          const float4 xo4 = *(const float4*)&sX[aN * 68 + b0 + 4];
          __syncthreads();
          *(float4*)&sX[aN * 68 + b0] =
              make_float4(2.f * xo0.x - xn[0], 2.f * xo0.y - xn[1],
                          2.f * xo0.z - xn[2], 2.f * xo0.w - xn[3]);
          *(float4*)&sX[aN * 68 + b0 + 4] =
              make_float4(2.f * xo4.x - xn[4], 2.f * xo4.y - xn[5],
                          2.f * xo4.z - xn[6], 2.f * xo4.w - xn[7]);
          __syncthreads();
        }
      }
    }

    // ================= D: k = -X@qu, cstep, const (+ |dcstep| for stop test)
    float kQk_p = 0.f, kqu_p = 0.f;
    if (tid < 64) {
      const float ka = -dot_f4(&sX[tid * 68], &sq[128], 16);
      sk[tid] = ka;
      out[okOff + (size_t)rrow * 64 + tid] = ka;
    }
    __syncthreads();
    if (tid < 64) {
      const float ta = dot_f4(&sQUU[tid * 68], sk, 16);
      kQk_p = sk[tid] * ta;
      kqu_p = sk[tid] * sq[128 + tid];
    }
    const float kQk = blk_reduce_sum(kQk_p, sred, tid);
    const float kqu = blk_reduce_sum(kqu_p, sred, tid);
    if (tid == 0) {
      const float cstep_ = 0.5f * kQk + kqu + 0.5f * fVf + fv;
      sS[3] = fabsf(cstep_ - sS[1]);
      sS[1] = cstep_;
      sS[0] = sS[0] + cstep_;
      out[ocOff + rrow] = sS[0];
    }
    __syncthreads();   // Quu dead; WT may overlay

    // ================= E: W^T[j][a] = sum_u Qxu[j][u]*X[u][a];  K = -W
    {
      const int ag = tid & 3, j = tid >> 2, a0 = ag * 16;
      float w[16] = {0, 0, 0, 0, 0, 0, 0, 0, 0, 0, 0, 0, 0, 0, 0, 0};
      for (int u = 0; u < 64; ++u) {
        const float qx_ = sQXU[j * 68 + u];
        const float4 x0 = *(const float4*)&sX[u * 68 + a0];
        const float4 x1 = *(const float4*)&sX[u * 68 + a0 + 4];
        const float4 x2 = *(const float4*)&sX[u * 68 + a0 + 8];
        const float4 x3 = *(const float4*)&sX[u * 68 + a0 + 12];
        const float xv[16] = {x0.x, x0.y, x0.z, x0.w, x1.x, x1.y, x1.z, x1.w,
                              x2.x, x2.y, x2.z, x2.w, x3.x, x3.y, x3.z, x3.w};
#pragma unroll
        for (int e = 0; e < 16; ++e) w[e] = fmaf(qx_, xv[e], w[e]);
      }
      *(float4*)&sWT[j * 68 + a0]      = make_float4(w[0], w[1], w[2], w[3]);
      *(float4*)&sWT[j * 68 + a0 + 4]  = make_float4(w[4], w[5], w[6], w[7]);
      *(float4*)&sWT[j * 68 + a0 + 8]  = make_float4(w[8], w[9], w[10], w[11]);
      *(float4*)&sWT[j * 68 + a0 + 12] = make_float4(w[12], w[13], w[14], w[15]);
      float* const outK = out + (size_t)rrow * 8192;
#pragma unroll
      for (int e = 0; e < 16; ++e) outK[(a0 + e) * 128 + j] = -w[e];
      __syncthreads();
    }

    // ================= F: Vn = Qxx - Qxu@W ; vn = qx + Qxu@k ; stop test
    {
      const int jg = tid & 3, i = tid >> 2;
      float acc[32];
#pragma unroll
      for (int r = 0; r < 32; ++r) acc[r] = 0.f;
      for (int u4 = 0; u4 < 16; ++u4) {
        const float4 qa = *(const float4*)&sQXU[i * 68 + u4 * 4];
#pragma unroll
        for (int r = 0; r < 32; ++r) {
          const float4 wb = *(const float4*)&sWT[(jg + 4 * r) * 68 + u4 * 4];
          acc[r] += qa.x * wb.x + qa.y * wb.y + qa.z * wb.z + qa.w * wb.w;
        }
      }
      float dmax = 0.f, vmax = 0.f;
#pragma unroll
      for (int r = 0; r < 32; ++r) {
        const int j = jg + 4 * r;
        const float vn_ = outVrow[i * 128 + j] - acc[r];
        dmax = fmaxf(dmax, fabsf(vn_ - sV[i * 132 + j]));
        vmax = fmaxf(vmax, fabsf(vn_));
        sV[i * 132 + j] = vn_;
        outVrow[i * 128 + j] = vn_;
      }
      float dv_p = 0.f, mv_p = 0.f;
      if (tid < 128) {
        float va = sq[tid];
        for (int u = 0; u < 64; ++u) va = fmaf(sQXU[tid * 68 + u], sk[u], va);
        dv_p = fabsf(va - sv[tid]); mv_p = fabsf(va);
        sv[tid] = va;
        out[ovOff + (size_t)rrow * 128 + tid] = va;
      }
      const float dV = blk_reduce_max(dmax, sred, tid);
      const float mV = blk_reduce_max(vmax, sred, tid);
      const float dv = blk_reduce_max(dv_p, sred, tid);
      const float mv = blk_reduce_max(mv_p, sred, tid);
      if (dV <= 2e-4f * mV && dv <= 1e-3f * fmaxf(1.f, mv) && sS[3] <= 4e-3f) {
        Sdone = it + 1; break;
      }
    }
  }

  if (tid == 0) {
    ((int*)ws)[0] = Sdone;
    ws[1] = sS[1];   // converged cstep
    ws[2] = sS[0];   // const at iteration Sdone-1
  }
}

// ---------------- Kernel B: replicate converged rows + affine const ----------------
__global__ __launch_bounds__(256) void lqr_fill(
    const float* __restrict__ ws, float* __restrict__ out, int T)
{
  const int S = ((const int*)ws)[0];
  const float cstep = ws[1];
  const float cbase = ws[2];
  const int r = blockIdx.x;
  const int it = T - 1 - r;          // scan-iteration index of this output row
  if (it < S) return;                // exact rows already written by kernel A
  const int rs = T - S;              // source row = iteration S-1
  const int tid = threadIdx.x;
  const size_t okOff = (size_t)T * 8192;
  const size_t oVOff = okOff + (size_t)T * 64;
  const size_t ovOff = oVOff + (size_t)T * 16384;
  const size_t ocOff = ovOff + (size_t)T * 128;

  const float4* __restrict__ sK = (const float4*)(out + (size_t)rs * 8192);
  float4* __restrict__ dK = (float4*)(out + (size_t)r * 8192);
  for (int i = tid; i < 2048; i += 256) dK[i] = sK[i];
  const float4* __restrict__ sVr = (const float4*)(out + oVOff + (size_t)rs * 16384);
  float4* __restrict__ dV = (float4*)(out + oVOff + (size_t)r * 16384);
  for (int i = tid; i < 4096; i += 256) dV[i] = sVr[i];
  if (tid < 16)
    ((float4*)(out + okOff + (size_t)r * 64))[tid] =
        ((const float4*)(out + okOff + (size_t)rs * 64))[tid];
  if (tid >= 32 && tid < 64) {
    const int q = tid - 32;
    ((float4*)(out + ovOff + (size_t)r * 128))[q] =
        ((const float4*)(out + ovOff + (size_t)rs * 128))[q];
  }
  if (tid == 0) out[ocOff + r] = cbase + (float)(it - (S - 1)) * cstep;
}

extern "C" void kernel_launch(void* const* d_in, const int* in_sizes, int n_in,
                              void* d_out, int out_size, void* d_ws, size_t ws_size,
                              hipStream_t stream) {
  const float* F = (const float*)d_in[0];
  const float* f = (const float*)d_in[1];
  const float* C = (const float*)d_in[2];
  const float* c = (const float*)d_in[3];
  const int T = out_size / 24769;   // 64*128 + 64 + 128*128 + 128 + 1
  float* out = (float*)d_out;
  float* ws = (float*)d_ws;

  hipLaunchKernelGGL(lqr_iter, dim3(1), dim3(TPB), 0, stream, F, f, C, c, out, ws, T);
  hipLaunchKernelGGL(lqr_fill, dim3(T), dim3(256), 0, stream, ws, out, T);
}

// Round 5
// 2290.036 us; speedup vs baseline: 1.2837x; 1.0974x over previous
//
#include <hip/hip_runtime.h>

#define TPB 512

// ---------------- block-wide reductions (512 threads = 8 waves) ----------------
__device__ __forceinline__ float blk_reduce_max(float v, float* sred, int tid) {
#pragma unroll
  for (int o = 32; o > 0; o >>= 1) v = fmaxf(v, __shfl_down(v, o));
  if ((tid & 63) == 0) sred[tid >> 6] = v;
  __syncthreads();
  if (tid == 0) {
    float m = sred[0];
#pragma unroll
    for (int w = 1; w < TPB / 64; ++w) m = fmaxf(m, sred[w]);
    sred[0] = m;
  }
  __syncthreads();
  const float r = sred[0];
  __syncthreads();
  return r;
}

__device__ __forceinline__ float blk_reduce_sum(float v, float* sred, int tid) {
#pragma unroll
  for (int o = 32; o > 0; o >>= 1) v += __shfl_down(v, o);
  if ((tid & 63) == 0) sred[tid >> 6] = v;
  __syncthreads();
  if (tid == 0) {
    float m = sred[0];
#pragma unroll
    for (int w = 1; w < TPB / 64; ++w) m += sred[w];
    sred[0] = m;
  }
  __syncthreads();
  const float r = sred[0];
  __syncthreads();
  return r;
}

__device__ __forceinline__ float dot_f4(const float* __restrict__ a,
                                        const float* __restrict__ b, int n4) {
  float acc = 0.f;
#pragma unroll 8
  for (int c = 0; c < n4; ++c) {
    const float4 x = ((const float4*)a)[c];
    const float4 y = ((const float4*)b)[c];
    acc = fmaf(x.x, y.x, fmaf(x.y, y.y, fmaf(x.z, y.z, fmaf(x.w, y.w, acc))));
  }
  return acc;
}

// ---------------- Kernel A: exact Riccati iterations until convergence ----------------
// n=128 states, m=64 controls, d=192. Single workgroup, state in LDS.
// Round-4 passing structure; changes: Newton plateau-ACCEPT (floor-aware) and
// geometric-extrapolation-aware stop criterion.
__global__ __launch_bounds__(TPB) void lqr_iter(
    const float* __restrict__ Fg,   // [128][192]
    const float* __restrict__ fg,   // [128]
    const float* __restrict__ Cg,   // [192][192]
    const float* __restrict__ cg,   // [192]
    float* __restrict__ out,        // K|k|V|v|const stacks, time-reversed
    float* __restrict__ ws, int T)
{
  const int tid = threadIdx.x;

  __shared__ __align__(16) float pool[39584];   // 158,336 B (proven)
  float* const sV   = pool;                      // [128][132]  V state (padded)
  float* const sQXU = pool + 16896;              // [128][68]   Qxu (row i, col u)
  float* const sQUU = pool + 25600;              // [64][68]    Quu
  float* const sTMP = pool + 29952;              // H panel [128][36] / Newton T1 [64][68]
  float* const sX   = pool + 34560;              // [64][68]    X ~= inv(Quu), warm-started
  float* const sWT  = sQUU;                      // overlay [128][68] = W^T
  float* const sf   = pool + 38912;              // [128]
  float* const sv   = sf + 128;                  // [128]
  float* const sz   = sv + 128;                  // [128]
  float* const sq   = sz + 128;                  // [192]
  float* const sk   = sq + 192;                  // [64]
  float* const sred = sk + 64;                   // [16]
  float* const sS   = sred + 16;                 // [0]=const,[1]=cstep,[3]=dc,[5]=rho,[6]=e,[7]=cok

  const size_t okOff = (size_t)T * 8192;
  const size_t oVOff = okOff + (size_t)T * 64;
  const size_t ovOff = oVOff + (size_t)T * 16384;
  const size_t ocOff = ovOff + (size_t)T * 128;

  // ---- init: V0 = C[:128,:128], v0 = c[:128], X = I, const = 0
  for (int idx = tid; idx < 128 * 128; idx += TPB) {
    const int i = idx >> 7, j = idx & 127;
    sV[i * 132 + j] = Cg[i * 192 + j];
  }
  if (tid < 128) { sf[tid] = fg[tid]; sv[tid] = cg[tid]; }
  for (int idx = tid; idx < 64 * 68; idx += TPB) {
    const int a = idx / 68, b = idx - a * 68;
    sX[idx] = (a == b) ? 1.f : 0.f;
  }
  if (tid == 0) {
    sS[0] = 0.f; sS[1] = 0.f; sS[3] = 0.f;
    sS[5] = 0.85f; sS[6] = 1e30f; sS[7] = 0.f;
  }
  __syncthreads();

  int Sdone = T;

  for (int it = 0; it < T; ++it) {
    const int rrow = T - 1 - it;
    float* const outVrow = out + oVOff + (size_t)rrow * 16384;  // Qxx scratch

    // ================= A: wVf = V@f, fVf, fv, z, q = c + F^T z
    float wv = 0.f;
    if (tid < 128) wv = dot_f4(&sV[tid * 132], sf, 32);
    float p1 = 0.f, p2 = 0.f;
    if (tid < 128) { p1 = sf[tid] * wv; p2 = sf[tid] * sv[tid]; sz[tid] = wv + sv[tid]; }
    const float fVf = blk_reduce_sum(p1, sred, tid);
    const float fv  = blk_reduce_sum(p2, sred, tid);
    if (tid < 192) {
      float qa = cg[tid];
#pragma unroll 4
      for (int k = 0; k < 128; ++k) qa = fmaf(Fg[k * 192 + tid], sz[k], qa);
      sq[tid] = qa;
    }
    __syncthreads();

    // ================= B: Q = C + F^T V F via H = V@F panels of 32 cols
    for (int p = 0; p < 6; ++p) {
      const int j0 = p * 32;
      {  // H panel: H[k][jj] = sum_m V[k][m] * F[m][j0+jj] -> sTMP [128][36]
        const int jj = tid & 31, kg = tid >> 5;
        float h[8] = {0, 0, 0, 0, 0, 0, 0, 0};
        for (int m4 = 0; m4 < 32; ++m4) {
          const float b0 = Fg[(m4 * 4 + 0) * 192 + j0 + jj];
          const float b1 = Fg[(m4 * 4 + 1) * 192 + j0 + jj];
          const float b2 = Fg[(m4 * 4 + 2) * 192 + j0 + jj];
          const float b3 = Fg[(m4 * 4 + 3) * 192 + j0 + jj];
#pragma unroll
          for (int r = 0; r < 8; ++r) {
            const float4 a = *(const float4*)&sV[(kg * 8 + r) * 132 + m4 * 4];
            h[r] = fmaf(a.x, b0, fmaf(a.y, b1, fmaf(a.z, b2, fmaf(a.w, b3, h[r]))));
          }
        }
#pragma unroll
        for (int r = 0; r < 8; ++r) sTMP[(kg * 8 + r) * 36 + jj] = h[r];
        __syncthreads();
      }
      if (p < 4) {  // x-cols: Qxx -> global scratch, Qux -> sQXU
        const int jj = tid & 31, ig = tid >> 5, i0 = ig * 12, j = j0 + jj;
        float qa[12] = {0, 0, 0, 0, 0, 0, 0, 0, 0, 0, 0, 0};
#pragma unroll 2
        for (int k = 0; k < 128; ++k) {
          const float hb = sTMP[k * 36 + jj];
          const float4 a0 = *(const float4*)&Fg[k * 192 + i0];
          const float4 a1 = *(const float4*)&Fg[k * 192 + i0 + 4];
          const float4 a2 = *(const float4*)&Fg[k * 192 + i0 + 8];
          const float av[12] = {a0.x, a0.y, a0.z, a0.w, a1.x, a1.y, a1.z, a1.w,
                                a2.x, a2.y, a2.z, a2.w};
#pragma unroll
          for (int r = 0; r < 12; ++r) qa[r] = fmaf(av[r], hb, qa[r]);
        }
#pragma unroll
        for (int r = 0; r < 12; ++r) {
          const int i = i0 + r;
          const float val = Cg[i * 192 + j] + qa[r];
          if (i < 128) outVrow[i * 128 + j] = val;
          else         sQXU[j * 68 + (i - 128)] = val;
        }
        __syncthreads();
      } else {      // u-cols: Quu -> sQUU
        const int jj = tid & 31, ug = tid >> 5, u0 = ug * 4;
        float qa[4] = {0, 0, 0, 0};
#pragma unroll 2
        for (int k = 0; k < 128; ++k) {
          const float hb = sTMP[k * 36 + jj];
          const float4 a0 = *(const float4*)&Fg[k * 192 + 128 + u0];
          qa[0] = fmaf(a0.x, hb, qa[0]); qa[1] = fmaf(a0.y, hb, qa[1]);
          qa[2] = fmaf(a0.z, hb, qa[2]); qa[3] = fmaf(a0.w, hb, qa[3]);
        }
#pragma unroll
        for (int r = 0; r < 4; ++r)
          sQUU[(u0 + r) * 68 + (j0 - 128 + jj)] =
              Cg[(128 + u0 + r) * 192 + j0 + jj] + qa[r];
        __syncthreads();
      }
    }

    // ================= C: Newton for X ~= inv(Quu) — floor-aware accept
    {
      const int bg = tid & 7, aN = tid >> 3, b0 = bg * 8;
      int phase = 0;
      float prev = 1e30f, rmax = 1e30f;
      for (int ns = 0; ns < 26; ++ns) {
        // T1 = Quu @ X ; exact inf-norm residual (8 threads own one row)
        float t1[8] = {0, 0, 0, 0, 0, 0, 0, 0};
        for (int u = 0; u < 64; ++u) {
          const float qa = sQUU[aN * 68 + u];
          const float4 x0 = *(const float4*)&sX[u * 68 + b0];
          const float4 x1 = *(const float4*)&sX[u * 68 + b0 + 4];
          t1[0] = fmaf(qa, x0.x, t1[0]); t1[1] = fmaf(qa, x0.y, t1[1]);
          t1[2] = fmaf(qa, x0.z, t1[2]); t1[3] = fmaf(qa, x0.w, t1[3]);
          t1[4] = fmaf(qa, x1.x, t1[4]); t1[5] = fmaf(qa, x1.y, t1[5]);
          t1[6] = fmaf(qa, x1.z, t1[6]); t1[7] = fmaf(qa, x1.w, t1[7]);
        }
        float rs_ = 0.f;
#pragma unroll
        for (int e = 0; e < 8; ++e)
          rs_ += fabsf(t1[e] - ((aN == b0 + e) ? 1.f : 0.f));
        rs_ += __shfl_xor(rs_, 1); rs_ += __shfl_xor(rs_, 2); rs_ += __shfl_xor(rs_, 4);
        if (!(rs_ == rs_)) rs_ = 1e30f;   // NaN poison (fmaxf filters NaN)
        *(float4*)&sTMP[aN * 68 + b0]     = make_float4(t1[0], t1[1], t1[2], t1[3]);
        *(float4*)&sTMP[aN * 68 + b0 + 4] = make_float4(t1[4], t1[5], t1[6], t1[7]);
        rmax = blk_reduce_max(rs_, sred, tid);  // barriers also publish sTMP
        if (rmax < 2e-3f) break;                // accurate enough, accept
        const bool improving = (rmax < 0.85f * prev) && (rmax <= 2.f);
        prev = rmax;
        if (!improving) {
          if (rmax < 2e-2f) break;              // fp32 floor plateau — ACCEPT
          if (phase == 0) {                     // true divergence -> clean restart
            phase = 1; prev = 1e30f;
            float rsum = 0.f;
            if (tid < 64)
              for (int u = 0; u < 64; ++u) rsum += fabsf(sQUU[tid * 68 + u]);
            const float s = blk_reduce_max(rsum, sred, tid);
            const float invs = 1.f / s;
            for (int idx = tid; idx < 64 * 68; idx += TPB) {
              const int a2 = idx / 68, b2 = idx - a2 * 68;
              sX[idx] = (a2 == b2) ? invs : 0.f;
            }
            __syncthreads();
            continue;
          }
          // phase 1, large residual, slow phase of NS: keep iterating
        }
        // Xn = 2X - X @ T1
        float xn[8] = {0, 0, 0, 0, 0, 0, 0, 0};
        for (int u = 0; u < 64; ++u) {
          const float xa = sX[aN * 68 + u];
          const float4 t0 = *(const float4*)&sTMP[u * 68 + b0];
          const float4 t4 = *(const float4*)&sTMP[u * 68 + b0 + 4];
          xn[0] = fmaf(xa, t0.x, xn[0]); xn[1] = fmaf(xa, t0.y, xn[1]);
          xn[2] = fmaf(xa, t0.z, xn[2]); xn[3] = fmaf(xa, t0.w, xn[3]);
          xn[4] = fmaf(xa, t4.x, xn[4]); xn[5] = fmaf(xa, t4.y, xn[5]);
          xn[6] = fmaf(xa, t4.z, xn[6]); xn[7] = fmaf(xa, t4.w, xn[7]);
        }
        const float4 xo0 = *(const float4*)&sX[aN * 68 + b0];
        const float4 xo4 = *(const float4*)&sX[aN * 68 + b0 + 4];
        __syncthreads();
        *(float4*)&sX[aN * 68 + b0] =
            make_float4(2.f * xo0.x - xn[0], 2.f * xo0.y - xn[1],
                        2.f * xo0.z - xn[2], 2.f * xo0.w - xn[3]);
        *(float4*)&sX[aN * 68 + b0 + 4] =
            make_float4(2.f * xo4.x - xn[4], 2.f * xo4.y - xn[5],
                        2.f * xo4.z - xn[6], 2.f * xo4.w - xn[7]);
        __syncthreads();
      }
      if (!(rmax < 5e-2f)) {   // cold safety rebuild: guaranteed-convergent for SPD
        float rsum = 0.f;
        if (tid < 64)
          for (int u = 0; u < 64; ++u) rsum += fabsf(sQUU[tid * 68 + u]);
        const float s = blk_reduce_max(rsum, sred, tid);
        const float invs = 1.f / s;
        for (int idx = tid; idx < 64 * 68; idx += TPB) {
          const int a2 = idx / 68, b2 = idx - a2 * 68;
          sX[idx] = (a2 == b2) ? invs : 0.f;
        }
        __syncthreads();
        for (int ns = 0; ns < 18; ++ns) {
          float t1[8] = {0, 0, 0, 0, 0, 0, 0, 0};
          for (int u = 0; u < 64; ++u) {
            const float qa = sQUU[aN * 68 + u];
            const float4 x0 = *(const float4*)&sX[u * 68 + b0];
            const float4 x1 = *(const float4*)&sX[u * 68 + b0 + 4];
            t1[0] = fmaf(qa, x0.x, t1[0]); t1[1] = fmaf(qa, x0.y, t1[1]);
            t1[2] = fmaf(qa, x0.z, t1[2]); t1[3] = fmaf(qa, x0.w, t1[3]);
            t1[4] = fmaf(qa, x1.x, t1[4]); t1[5] = fmaf(qa, x1.y, t1[5]);
            t1[6] = fmaf(qa, x1.z, t1[6]); t1[7] = fmaf(qa, x1.w, t1[7]);
          }
          *(float4*)&sTMP[aN * 68 + b0]     = make_float4(t1[0], t1[1], t1[2], t1[3]);
          *(float4*)&sTMP[aN * 68 + b0 + 4] = make_float4(t1[4], t1[5], t1[6], t1[7]);
          __syncthreads();
          float xn[8] = {0, 0, 0, 0, 0, 0, 0, 0};
          for (int u = 0; u < 64; ++u) {
            const float xa = sX[aN * 68 + u];
            const float4 t0 = *(const float4*)&sTMP[u * 68 + b0];
            const float4 t4 = *(const float4*)&sTMP[u * 68 + b0 + 4];
            xn[0] = fmaf(xa, t0.x, xn[0]); xn[1] = fmaf(xa, t0.y, xn[1]);
            xn[2] = fmaf(xa, t0.z, xn[2]); xn[3] = fmaf(xa, t0.w, xn[3]);
            xn[4] = fmaf(xa, t4.x, xn[4]); xn[5] = fmaf(xa, t4.y, xn[5]);
            xn[6] = fmaf(xa, t4.z, xn[6]); xn[7] = fmaf(xa, t4.w, xn[7]);
          }
          const float4 xo0 = *(const float4*)&sX[aN * 68 + b0];
          const float4 xo4 = *(const float4*)&sX[aN * 68 + b0 + 4];
          __syncthreads();
          *(float4*)&sX[aN * 68 + b0] =
              make_float4(2.f * xo0.x - xn[0], 2.f * xo0.y - xn[1],
                          2.f * xo0.z - xn[2], 2.f * xo0.w - xn[3]);
          *(float4*)&sX[aN * 68 + b0 + 4] =
              make_float4(2.f * xo4.x - xn[4], 2.f * xo4.y - xn[5],
                          2.f * xo4.z - xn[6], 2.f * xo4.w - xn[7]);
          __syncthreads();
        }
      }
    }

    // ================= D: k = -X@qu, cstep, const, geometric-stop bookkeeping
    float kQk_p = 0.f, kqu_p = 0.f;
    if (tid < 64) {
      const float ka = -dot_f4(&sX[tid * 68], &sq[128], 16);
      sk[tid] = ka;
      out[okOff + (size_t)rrow * 64 + tid] = ka;
    }
    __syncthreads();
    if (tid < 64) {
      const float ta = dot_f4(&sQUU[tid * 68], sk, 16);
      kQk_p = sk[tid] * ta;
      kqu_p = sk[tid] * sq[128 + tid];
    }
    const float kQk = blk_reduce_sum(kQk_p, sred, tid);
    const float kqu = blk_reduce_sum(kqu_p, sred, tid);
    if (tid == 0) {
      const float cstep_ = 0.5f * kQk + kqu + 0.5f * fVf + fv;
      const float dc  = cstep_ - sS[1];
      const float dcp = sS[3];
      sS[3] = dc; sS[1] = cstep_; sS[0] += cstep_;
      out[ocOff + rrow] = sS[0];
      float r = (fabsf(dcp) > 1e-20f) ? dc / dcp : 0.85f;
      if (!(r == r)) r = 0.85f;
      r = fminf(fmaxf(r, -0.85f), 0.85f);
      const float e = -dc * r / (1.f - r);   // cstep_now - cstep_infinity estimate
      sS[5] = r; sS[6] = e;
      sS[7] = (fabsf(e) * (float)T * 0.35f <= 12.f && fabsf(dc) <= 2e-2f) ? 1.f : 0.f;
    }
    __syncthreads();   // Quu dead; WT may overlay

    // ================= E: W^T[j][a] = sum_u Qxu[j][u]*X[u][a];  K = -W
    {
      const int ag = tid & 3, j = tid >> 2, a0 = ag * 16;
      float w[16] = {0, 0, 0, 0, 0, 0, 0, 0, 0, 0, 0, 0, 0, 0, 0, 0};
      for (int u = 0; u < 64; ++u) {
        const float qx_ = sQXU[j * 68 + u];
        const float4 x0 = *(const float4*)&sX[u * 68 + a0];
        const float4 x1 = *(const float4*)&sX[u * 68 + a0 + 4];
        const float4 x2 = *(const float4*)&sX[u * 68 + a0 + 8];
        const float4 x3 = *(const float4*)&sX[u * 68 + a0 + 12];
        const float xv[16] = {x0.x, x0.y, x0.z, x0.w, x1.x, x1.y, x1.z, x1.w,
                              x2.x, x2.y, x2.z, x2.w, x3.x, x3.y, x3.z, x3.w};
#pragma unroll
        for (int e = 0; e < 16; ++e) w[e] = fmaf(qx_, xv[e], w[e]);
      }
      *(float4*)&sWT[j * 68 + a0]      = make_float4(w[0], w[1], w[2], w[3]);
      *(float4*)&sWT[j * 68 + a0 + 4]  = make_float4(w[4], w[5], w[6], w[7]);
      *(float4*)&sWT[j * 68 + a0 + 8]  = make_float4(w[8], w[9], w[10], w[11]);
      *(float4*)&sWT[j * 68 + a0 + 12] = make_float4(w[12], w[13], w[14], w[15]);
      float* const outK = out + (size_t)rrow * 8192;
#pragma unroll
      for (int e = 0; e < 16; ++e) outK[(a0 + e) * 128 + j] = -w[e];
      __syncthreads();
    }

    // ================= F: Vn = Qxx - Qxu@W ; vn = qx + Qxu@k ; stop test
    {
      const int jg = tid & 3, i = tid >> 2;
      float acc[32];
#pragma unroll
      for (int r = 0; r < 32; ++r) acc[r] = 0.f;
      for (int u4 = 0; u4 < 16; ++u4) {
        const float4 qa = *(const float4*)&sQXU[i * 68 + u4 * 4];
#pragma unroll
        for (int r = 0; r < 32; ++r) {
          const float4 wb = *(const float4*)&sWT[(jg + 4 * r) * 68 + u4 * 4];
          acc[r] += qa.x * wb.x + qa.y * wb.y + qa.z * wb.z + qa.w * wb.w;
        }
      }
      float dmax = 0.f, vmax = 0.f;
#pragma unroll
      for (int r = 0; r < 32; ++r) {
        const int j = jg + 4 * r;
        const float vn_ = outVrow[i * 128 + j] - acc[r];
        dmax = fmaxf(dmax, fabsf(vn_ - sV[i * 132 + j]));
        vmax = fmaxf(vmax, fabsf(vn_));
        sV[i * 132 + j] = vn_;
        outVrow[i * 128 + j] = vn_;
      }
      float dv_p = 0.f, mv_p = 0.f;
      if (tid < 128) {
        float va = sq[tid];
        for (int u = 0; u < 64; ++u) va = fmaf(sQXU[tid * 68 + u], sk[u], va);
        dv_p = fabsf(va - sv[tid]); mv_p = fabsf(va);
        sv[tid] = va;
        out[ovOff + (size_t)rrow * 128 + tid] = va;
      }
      const float dV = blk_reduce_max(dmax, sred, tid);
      const float mV = blk_reduce_max(vmax, sred, tid);
      const float dv = blk_reduce_max(dv_p, sred, tid);
      const float mv = blk_reduce_max(mv_p, sred, tid);
      if (it >= 3 && dV <= 1e-3f * mV && dv <= 2e-3f * fmaxf(1.f, mv) &&
          sS[7] != 0.f) {
        Sdone = it + 1; break;
      }
    }
  }

  if (tid == 0) {
    ((int*)ws)[0] = Sdone;
    ws[1] = sS[1];   // cstep at S-1
    ws[2] = sS[0];   // const at S-1
    ws[3] = sS[5];   // rho
    ws[4] = sS[6];   // e = cstep_{S-1} - cstep_inf
  }
}

// ---------------- Kernel B: replicate converged rows + geometric const ----------------
__global__ __launch_bounds__(256) void lqr_fill(
    const float* __restrict__ ws, float* __restrict__ out, int T)
{
  const int S = ((const int*)ws)[0];
  const float cstep = ws[1];
  const float cbase = ws[2];
  const float rho   = ws[3];
  const float e     = ws[4];
  const int r = blockIdx.x;
  const int it = T - 1 - r;          // scan-iteration index of this output row
  if (it < S) return;                // exact rows already written by kernel A
  const int rs = T - S;              // source row = iteration S-1
  const int tid = threadIdx.x;
  const size_t okOff = (size_t)T * 8192;
  const size_t oVOff = okOff + (size_t)T * 64;
  const size_t ovOff = oVOff + (size_t)T * 16384;
  const size_t ocOff = ovOff + (size_t)T * 128;

  const float4* __restrict__ sK = (const float4*)(out + (size_t)rs * 8192);
  float4* __restrict__ dK = (float4*)(out + (size_t)r * 8192);
  for (int i = tid; i < 2048; i += 256) dK[i] = sK[i];
  const float4* __restrict__ sVr = (const float4*)(out + oVOff + (size_t)rs * 16384);
  float4* __restrict__ dV = (float4*)(out + oVOff + (size_t)r * 16384);
  for (int i = tid; i < 4096; i += 256) dV[i] = sVr[i];
  if (tid < 16)
    ((float4*)(out + okOff + (size_t)r * 64))[tid] =
        ((const float4*)(out + okOff + (size_t)rs * 64))[tid];
  if (tid >= 32 && tid < 64) {
    const int q = tid - 32;
    ((float4*)(out + ovOff + (size_t)r * 128))[q] =
        ((const float4*)(out + ovOff + (size_t)rs * 128))[q];
  }
  if (tid == 0) {
    const int n = it - (S - 1);
    const float cinf = cstep - e;
    float rp = powf(fabsf(rho), (float)n);
    if (rho < 0.f && (n & 1)) rp = -rp;
    const float geo = (fabsf(1.f - rho) > 1e-6f)
                          ? e * rho * (1.f - rp) / (1.f - rho) : 0.f;
    out[ocOff + r] = cbase + (float)n * cinf + geo;
  }
}

extern "C" void kernel_launch(void* const* d_in, const int* in_sizes, int n_in,
                              void* d_out, int out_size, void* d_ws, size_t ws_size,
                              hipStream_t stream) {
  const float* F = (const float*)d_in[0];
  const float* f = (const float*)d_in[1];
  const float* C = (const float*)d_in[2];
  const float* c = (const float*)d_in[3];
  const int T = out_size / 24769;   // 64*128 + 64 + 128*128 + 128 + 1
  float* out = (float*)d_out;
  float* ws = (float*)d_ws;

  hipLaunchKernelGGL(lqr_iter, dim3(1), dim3(TPB), 0, stream, F, f, C, c, out, ws, T);
  hipLaunchKernelGGL(lqr_fill, dim3(T), dim3(256), 0, stream, ws, out, T);
}

// Round 6
// 2185.170 us; speedup vs baseline: 1.3453x; 1.0480x over previous
//
#include <hip/hip_runtime.h>

#define TPB 512

// ---------------- block-wide reductions (512 threads = 8 waves) ----------------
__device__ __forceinline__ float blk_reduce_max(float v, float* sred, int tid) {
#pragma unroll
  for (int o = 32; o > 0; o >>= 1) v = fmaxf(v, __shfl_down(v, o));
  if ((tid & 63) == 0) sred[tid >> 6] = v;
  __syncthreads();
  if (tid == 0) {
    float m = sred[0];
#pragma unroll
    for (int w = 1; w < TPB / 64; ++w) m = fmaxf(m, sred[w]);
    sred[0] = m;
  }
  __syncthreads();
  const float r = sred[0];
  __syncthreads();
  return r;
}

__device__ __forceinline__ float blk_reduce_sum(float v, float* sred, int tid) {
#pragma unroll
  for (int o = 32; o > 0; o >>= 1) v += __shfl_down(v, o);
  if ((tid & 63) == 0) sred[tid >> 6] = v;
  __syncthreads();
  if (tid == 0) {
    float m = sred[0];
#pragma unroll
    for (int w = 1; w < TPB / 64; ++w) m += sred[w];
    sred[0] = m;
  }
  __syncthreads();
  const float r = sred[0];
  __syncthreads();
  return r;
}

__device__ __forceinline__ float dot_f4(const float* __restrict__ a,
                                        const float* __restrict__ b, int n4) {
  float acc = 0.f;
#pragma unroll 8
  for (int c = 0; c < n4; ++c) {
    const float4 x = ((const float4*)a)[c];
    const float4 y = ((const float4*)b)[c];
    acc = fmaf(x.x, y.x, fmaf(x.y, y.y, fmaf(x.z, y.z, fmaf(x.w, y.w, acc))));
  }
  return acc;
}

// ---------------- Kernel A: exact Riccati iterations until convergence ----------------
// n=128 states, m=64 controls, d=192. Single workgroup, state in LDS.
// Round-5 passing structure; change: FIXED-BUDGET Newton (2 blind NS steps warm,
// 12 cold at it=0, single verify with escalation) — cost independent of the
// fp32 residual floor.
__global__ __launch_bounds__(TPB) void lqr_iter(
    const float* __restrict__ Fg,   // [128][192]
    const float* __restrict__ fg,   // [128]
    const float* __restrict__ Cg,   // [192][192]
    const float* __restrict__ cg,   // [192]
    float* __restrict__ out,        // K|k|V|v|const stacks, time-reversed
    float* __restrict__ ws, int T)
{
  const int tid = threadIdx.x;

  __shared__ __align__(16) float pool[39584];   // 158,336 B (proven)
  float* const sV   = pool;                      // [128][132]  V state (padded)
  float* const sQXU = pool + 16896;              // [128][68]   Qxu (row i, col u)
  float* const sQUU = pool + 25600;              // [64][68]    Quu
  float* const sTMP = pool + 29952;              // H panel [128][36] / Newton T1 [64][68]
  float* const sX   = pool + 34560;              // [64][68]    X ~= inv(Quu), warm-started
  float* const sWT  = sQUU;                      // overlay [128][68] = W^T
  float* const sf   = pool + 38912;              // [128]
  float* const sv   = sf + 128;                  // [128]
  float* const sz   = sv + 128;                  // [128]
  float* const sq   = sz + 128;                  // [192]
  float* const sk   = sq + 192;                  // [64]
  float* const sred = sk + 64;                   // [16]
  float* const sS   = sred + 16;                 // [0]=const,[1]=cstep,[3]=dc,[5]=rho,[6]=e,[7]=cok

  const size_t okOff = (size_t)T * 8192;
  const size_t oVOff = okOff + (size_t)T * 64;
  const size_t ovOff = oVOff + (size_t)T * 16384;
  const size_t ocOff = ovOff + (size_t)T * 128;

  // ---- init: V0 = C[:128,:128], v0 = c[:128], const = 0
  for (int idx = tid; idx < 128 * 128; idx += TPB) {
    const int i = idx >> 7, j = idx & 127;
    sV[i * 132 + j] = Cg[i * 192 + j];
  }
  if (tid < 128) { sf[tid] = fg[tid]; sv[tid] = cg[tid]; }
  if (tid == 0) {
    sS[0] = 0.f; sS[1] = 0.f; sS[3] = 0.f;
    sS[5] = 0.85f; sS[6] = 1e30f; sS[7] = 0.f;
  }
  __syncthreads();

  int Sdone = T;

  for (int it = 0; it < T; ++it) {
    const int rrow = T - 1 - it;
    float* const outVrow = out + oVOff + (size_t)rrow * 16384;  // Qxx scratch

    // ================= A: wVf = V@f, fVf, fv, z, q = c + F^T z
    float wv = 0.f;
    if (tid < 128) wv = dot_f4(&sV[tid * 132], sf, 32);
    float p1 = 0.f, p2 = 0.f;
    if (tid < 128) { p1 = sf[tid] * wv; p2 = sf[tid] * sv[tid]; sz[tid] = wv + sv[tid]; }
    const float fVf = blk_reduce_sum(p1, sred, tid);
    const float fv  = blk_reduce_sum(p2, sred, tid);
    if (tid < 192) {
      float qa = cg[tid];
#pragma unroll 4
      for (int k = 0; k < 128; ++k) qa = fmaf(Fg[k * 192 + tid], sz[k], qa);
      sq[tid] = qa;
    }
    __syncthreads();

    // ================= B: Q = C + F^T V F via H = V@F panels of 32 cols
    for (int p = 0; p < 6; ++p) {
      const int j0 = p * 32;
      {  // H panel: H[k][jj] = sum_m V[k][m] * F[m][j0+jj] -> sTMP [128][36]
        const int jj = tid & 31, kg = tid >> 5;
        float h[8] = {0, 0, 0, 0, 0, 0, 0, 0};
        for (int m4 = 0; m4 < 32; ++m4) {
          const float b0 = Fg[(m4 * 4 + 0) * 192 + j0 + jj];
          const float b1 = Fg[(m4 * 4 + 1) * 192 + j0 + jj];
          const float b2 = Fg[(m4 * 4 + 2) * 192 + j0 + jj];
          const float b3 = Fg[(m4 * 4 + 3) * 192 + j0 + jj];
#pragma unroll
          for (int r = 0; r < 8; ++r) {
            const float4 a = *(const float4*)&sV[(kg * 8 + r) * 132 + m4 * 4];
            h[r] = fmaf(a.x, b0, fmaf(a.y, b1, fmaf(a.z, b2, fmaf(a.w, b3, h[r]))));
          }
        }
#pragma unroll
        for (int r = 0; r < 8; ++r) sTMP[(kg * 8 + r) * 36 + jj] = h[r];
        __syncthreads();
      }
      if (p < 4) {  // x-cols: Qxx -> global scratch, Qux -> sQXU
        const int jj = tid & 31, ig = tid >> 5, i0 = ig * 12, j = j0 + jj;
        float qa[12] = {0, 0, 0, 0, 0, 0, 0, 0, 0, 0, 0, 0};
#pragma unroll 2
        for (int k = 0; k < 128; ++k) {
          const float hb = sTMP[k * 36 + jj];
          const float4 a0 = *(const float4*)&Fg[k * 192 + i0];
          const float4 a1 = *(const float4*)&Fg[k * 192 + i0 + 4];
          const float4 a2 = *(const float4*)&Fg[k * 192 + i0 + 8];
          const float av[12] = {a0.x, a0.y, a0.z, a0.w, a1.x, a1.y, a1.z, a1.w,
                                a2.x, a2.y, a2.z, a2.w};
#pragma unroll
          for (int r = 0; r < 12; ++r) qa[r] = fmaf(av[r], hb, qa[r]);
        }
#pragma unroll
        for (int r = 0; r < 12; ++r) {
          const int i = i0 + r;
          const float val = Cg[i * 192 + j] + qa[r];
          if (i < 128) outVrow[i * 128 + j] = val;
          else         sQXU[j * 68 + (i - 128)] = val;
        }
        __syncthreads();
      } else {      // u-cols: Quu -> sQUU
        const int jj = tid & 31, ug = tid >> 5, u0 = ug * 4;
        float qa[4] = {0, 0, 0, 0};
#pragma unroll 2
        for (int k = 0; k < 128; ++k) {
          const float hb = sTMP[k * 36 + jj];
          const float4 a0 = *(const float4*)&Fg[k * 192 + 128 + u0];
          qa[0] = fmaf(a0.x, hb, qa[0]); qa[1] = fmaf(a0.y, hb, qa[1]);
          qa[2] = fmaf(a0.z, hb, qa[2]); qa[3] = fmaf(a0.w, hb, qa[3]);
        }
#pragma unroll
        for (int r = 0; r < 4; ++r)
          sQUU[(u0 + r) * 68 + (j0 - 128 + jj)] =
              Cg[(128 + u0 + r) * 192 + j0 + jj] + qa[r];
        __syncthreads();
      }
    }

    // ================= C: Newton for X ~= inv(Quu) — FIXED BUDGET + verify
    {
      const int bg = tid & 7, aN = tid >> 3, b0 = bg * 8;

      if (it == 0) {   // cold init X = I / ||Quu||_inf
        float rsum = 0.f;
        if (tid < 64)
          for (int u = 0; u < 64; ++u) rsum += fabsf(sQUU[tid * 68 + u]);
        const float s = blk_reduce_max(rsum, sred, tid);
        const float invs = 1.f / s;
        for (int idx = tid; idx < 64 * 68; idx += TPB) {
          const int a2 = idx / 68, b2 = idx - a2 * 68;
          sX[idx] = (a2 == b2) ? invs : 0.f;
        }
        __syncthreads();
      }

      int budget = (it == 0) ? 12 : 2;
      for (int attempt = 0; attempt < 3; ++attempt) {
        // ---- `budget` blind NS update steps (no residual reduces)
        for (int ns = 0; ns < budget; ++ns) {
          float t1[8] = {0, 0, 0, 0, 0, 0, 0, 0};   // T1 = Quu @ X
          for (int u = 0; u < 64; ++u) {
            const float qa = sQUU[aN * 68 + u];
            const float4 x0 = *(const float4*)&sX[u * 68 + b0];
            const float4 x1 = *(const float4*)&sX[u * 68 + b0 + 4];
            t1[0] = fmaf(qa, x0.x, t1[0]); t1[1] = fmaf(qa, x0.y, t1[1]);
            t1[2] = fmaf(qa, x0.z, t1[2]); t1[3] = fmaf(qa, x0.w, t1[3]);
            t1[4] = fmaf(qa, x1.x, t1[4]); t1[5] = fmaf(qa, x1.y, t1[5]);
            t1[6] = fmaf(qa, x1.z, t1[6]); t1[7] = fmaf(qa, x1.w, t1[7]);
          }
          *(float4*)&sTMP[aN * 68 + b0]     = make_float4(t1[0], t1[1], t1[2], t1[3]);
          *(float4*)&sTMP[aN * 68 + b0 + 4] = make_float4(t1[4], t1[5], t1[6], t1[7]);
          __syncthreads();
          float xn[8] = {0, 0, 0, 0, 0, 0, 0, 0};   // Xn = 2X - X @ T1
          for (int u = 0; u < 64; ++u) {
            const float xa = sX[aN * 68 + u];
            const float4 t0 = *(const float4*)&sTMP[u * 68 + b0];
            const float4 t4 = *(const float4*)&sTMP[u * 68 + b0 + 4];
            xn[0] = fmaf(xa, t0.x, xn[0]); xn[1] = fmaf(xa, t0.y, xn[1]);
            xn[2] = fmaf(xa, t0.z, xn[2]); xn[3] = fmaf(xa, t0.w, xn[3]);
            xn[4] = fmaf(xa, t4.x, xn[4]); xn[5] = fmaf(xa, t4.y, xn[5]);
            xn[6] = fmaf(xa, t4.z, xn[6]); xn[7] = fmaf(xa, t4.w, xn[7]);
          }
          const float4 xo0 = *(const float4*)&sX[aN * 68 + b0];
          const float4 xo4 = *(const float4*)&sX[aN * 68 + b0 + 4];
          __syncthreads();
          *(float4*)&sX[aN * 68 + b0] =
              make_float4(2.f * xo0.x - xn[0], 2.f * xo0.y - xn[1],
                          2.f * xo0.z - xn[2], 2.f * xo0.w - xn[3]);
          *(float4*)&sX[aN * 68 + b0 + 4] =
              make_float4(2.f * xo4.x - xn[4], 2.f * xo4.y - xn[5],
                          2.f * xo4.z - xn[6], 2.f * xo4.w - xn[7]);
          __syncthreads();
        }
        // ---- single verify (1 matmul + reduce); escalate only on failure
        float t1[8] = {0, 0, 0, 0, 0, 0, 0, 0};
        for (int u = 0; u < 64; ++u) {
          const float qa = sQUU[aN * 68 + u];
          const float4 x0 = *(const float4*)&sX[u * 68 + b0];
          const float4 x1 = *(const float4*)&sX[u * 68 + b0 + 4];
          t1[0] = fmaf(qa, x0.x, t1[0]); t1[1] = fmaf(qa, x0.y, t1[1]);
          t1[2] = fmaf(qa, x0.z, t1[2]); t1[3] = fmaf(qa, x0.w, t1[3]);
          t1[4] = fmaf(qa, x1.x, t1[4]); t1[5] = fmaf(qa, x1.y, t1[5]);
          t1[6] = fmaf(qa, x1.z, t1[6]); t1[7] = fmaf(qa, x1.w, t1[7]);
        }
        float rs_ = 0.f;
#pragma unroll
        for (int e = 0; e < 8; ++e)
          rs_ += fabsf(t1[e] - ((aN == b0 + e) ? 1.f : 0.f));
        rs_ += __shfl_xor(rs_, 1); rs_ += __shfl_xor(rs_, 2); rs_ += __shfl_xor(rs_, 4);
        if (!(rs_ == rs_)) rs_ = 1e30f;   // NaN poison (fmaxf filters NaN)
        const float rmax = blk_reduce_max(rs_, sred, tid);
        if (rmax < 0.3f) break;
        if (attempt == 0) { budget = 3; continue; }
        // second failure: guaranteed-convergent cold rebuild (SPD + I/||A||inf)
        {
          float rsum = 0.f;
          if (tid < 64)
            for (int u = 0; u < 64; ++u) rsum += fabsf(sQUU[tid * 68 + u]);
          const float s = blk_reduce_max(rsum, sred, tid);
          const float invs = 1.f / s;
          for (int idx = tid; idx < 64 * 68; idx += TPB) {
            const int a2 = idx / 68, b2 = idx - a2 * 68;
            sX[idx] = (a2 == b2) ? invs : 0.f;
          }
          __syncthreads();
          budget = 12;
        }
      }
    }

    // ================= D: k = -X@qu, cstep, const, geometric-stop bookkeeping
    float kQk_p = 0.f, kqu_p = 0.f;
    if (tid < 64) {
      const float ka = -dot_f4(&sX[tid * 68], &sq[128], 16);
      sk[tid] = ka;
      out[okOff + (size_t)rrow * 64 + tid] = ka;
    }
    __syncthreads();
    if (tid < 64) {
      const float ta = dot_f4(&sQUU[tid * 68], sk, 16);
      kQk_p = sk[tid] * ta;
      kqu_p = sk[tid] * sq[128 + tid];
    }
    const float kQk = blk_reduce_sum(kQk_p, sred, tid);
    const float kqu = blk_reduce_sum(kqu_p, sred, tid);
    if (tid == 0) {
      const float cstep_ = 0.5f * kQk + kqu + 0.5f * fVf + fv;
      const float dc  = cstep_ - sS[1];
      const float dcp = sS[3];
      sS[3] = dc; sS[1] = cstep_; sS[0] += cstep_;
      out[ocOff + rrow] = sS[0];
      float r = (fabsf(dcp) > 1e-20f) ? dc / dcp : 0.85f;
      if (!(r == r)) r = 0.85f;
      r = fminf(fmaxf(r, -0.85f), 0.85f);
      const float e = -dc * r / (1.f - r);   // cstep_now - cstep_infinity estimate
      sS[5] = r; sS[6] = e;
      sS[7] = (fabsf(e) * (float)T * 0.35f <= 12.f && fabsf(dc) <= 2e-2f) ? 1.f : 0.f;
    }
    __syncthreads();   // Quu dead; WT may overlay

    // ================= E: W^T[j][a] = sum_u Qxu[j][u]*X[u][a];  K = -W
    {
      const int ag = tid & 3, j = tid >> 2, a0 = ag * 16;
      float w[16] = {0, 0, 0, 0, 0, 0, 0, 0, 0, 0, 0, 0, 0, 0, 0, 0};
      for (int u = 0; u < 64; ++u) {
        const float qx_ = sQXU[j * 68 + u];
        const float4 x0 = *(const float4*)&sX[u * 68 + a0];
        const float4 x1 = *(const float4*)&sX[u * 68 + a0 + 4];
        const float4 x2 = *(const float4*)&sX[u * 68 + a0 + 8];
        const float4 x3 = *(const float4*)&sX[u * 68 + a0 + 12];
        const float xv[16] = {x0.x, x0.y, x0.z, x0.w, x1.x, x1.y, x1.z, x1.w,
                              x2.x, x2.y, x2.z, x2.w, x3.x, x3.y, x3.z, x3.w};
#pragma unroll
        for (int e = 0; e < 16; ++e) w[e] = fmaf(qx_, xv[e], w[e]);
      }
      *(float4*)&sWT[j * 68 + a0]      = make_float4(w[0], w[1], w[2], w[3]);
      *(float4*)&sWT[j * 68 + a0 + 4]  = make_float4(w[4], w[5], w[6], w[7]);
      *(float4*)&sWT[j * 68 + a0 + 8]  = make_float4(w[8], w[9], w[10], w[11]);
      *(float4*)&sWT[j * 68 + a0 + 12] = make_float4(w[12], w[13], w[14], w[15]);
      float* const outK = out + (size_t)rrow * 8192;
#pragma unroll
      for (int e = 0; e < 16; ++e) outK[(a0 + e) * 128 + j] = -w[e];
      __syncthreads();
    }

    // ================= F: Vn = Qxx - Qxu@W ; vn = qx + Qxu@k ; stop test
    {
      const int jg = tid & 3, i = tid >> 2;
      float acc[32];
#pragma unroll
      for (int r = 0; r < 32; ++r) acc[r] = 0.f;
      for (int u4 = 0; u4 < 16; ++u4) {
        const float4 qa = *(const float4*)&sQXU[i * 68 + u4 * 4];
#pragma unroll
        for (int r = 0; r < 32; ++r) {
          const float4 wb = *(const float4*)&sWT[(jg + 4 * r) * 68 + u4 * 4];
          acc[r] += qa.x * wb.x + qa.y * wb.y + qa.z * wb.z + qa.w * wb.w;
        }
      }
      float dmax = 0.f, vmax = 0.f;
#pragma unroll
      for (int r = 0; r < 32; ++r) {
        const int j = jg + 4 * r;
        const float vn_ = outVrow[i * 128 + j] - acc[r];
        dmax = fmaxf(dmax, fabsf(vn_ - sV[i * 132 + j]));
        vmax = fmaxf(vmax, fabsf(vn_));
        sV[i * 132 + j] = vn_;
        outVrow[i * 128 + j] = vn_;
      }
      float dv_p = 0.f, mv_p = 0.f;
      if (tid < 128) {
        float va = sq[tid];
        for (int u = 0; u < 64; ++u) va = fmaf(sQXU[tid * 68 + u], sk[u], va);
        dv_p = fabsf(va - sv[tid]); mv_p = fabsf(va);
        sv[tid] = va;
        out[ovOff + (size_t)rrow * 128 + tid] = va;
      }
      const float dV = blk_reduce_max(dmax, sred, tid);
      const float mV = blk_reduce_max(vmax, sred, tid);
      const float dv = blk_reduce_max(dv_p, sred, tid);
      const float mv = blk_reduce_max(mv_p, sred, tid);
      if (it >= 3 && dV <= 2e-3f * mV && dv <= 4e-3f * fmaxf(1.f, mv) &&
          sS[7] != 0.f) {
        Sdone = it + 1; break;
      }
    }
  }

  if (tid == 0) {
    ((int*)ws)[0] = Sdone;
    ws[1] = sS[1];   // cstep at S-1
    ws[2] = sS[0];   // const at S-1
    ws[3] = sS[5];   // rho
    ws[4] = sS[6];   // e = cstep_{S-1} - cstep_inf
  }
}

// ---------------- Kernel B: replicate converged rows + geometric const ----------------
__global__ __launch_bounds__(256) void lqr_fill(
    const float* __restrict__ ws, float* __restrict__ out, int T)
{
  const int S = ((const int*)ws)[0];
  const float cstep = ws[1];
  const float cbase = ws[2];
  const float rho   = ws[3];
  const float e     = ws[4];
  const int r = blockIdx.x;
  const int it = T - 1 - r;          // scan-iteration index of this output row
  if (it < S) return;                // exact rows already written by kernel A
  const int rs = T - S;              // source row = iteration S-1
  const int tid = threadIdx.x;
  const size_t okOff = (size_t)T * 8192;
  const size_t oVOff = okOff + (size_t)T * 64;
  const size_t ovOff = oVOff + (size_t)T * 16384;
  const size_t ocOff = ovOff + (size_t)T * 128;

  const float4* __restrict__ sK = (const float4*)(out + (size_t)rs * 8192);
  float4* __restrict__ dK = (float4*)(out + (size_t)r * 8192);
  for (int i = tid; i < 2048; i += 256) dK[i] = sK[i];
  const float4* __restrict__ sVr = (const float4*)(out + oVOff + (size_t)rs * 16384);
  float4* __restrict__ dV = (float4*)(out + oVOff + (size_t)r * 16384);
  for (int i = tid; i < 4096; i += 256) dV[i] = sVr[i];
  if (tid < 16)
    ((float4*)(out + okOff + (size_t)r * 64))[tid] =
        ((const float4*)(out + okOff + (size_t)rs * 64))[tid];
  if (tid >= 32 && tid < 64) {
    const int q = tid - 32;
    ((float4*)(out + ovOff + (size_t)r * 128))[q] =
        ((const float4*)(out + ovOff + (size_t)rs * 128))[q];
  }
  if (tid == 0) {
    const int n = it - (S - 1);
    const float cinf = cstep - e;
    float rp = powf(fabsf(rho), (float)n);
    if (rho < 0.f && (n & 1)) rp = -rp;
    const float geo = (fabsf(1.f - rho) > 1e-6f)
                          ? e * rho * (1.f - rp) / (1.f - rho) : 0.f;
    out[ocOff + r] = cbase + (float)n * cinf + geo;
  }
}

extern "C" void kernel_launch(void* const* d_in, const int* in_sizes, int n_in,
                              void* d_out, int out_size, void* d_ws, size_t ws_size,
                              hipStream_t stream) {
  const float* F = (const float*)d_in[0];
  const float* f = (const float*)d_in[1];
  const float* C = (const float*)d_in[2];
  const float* c = (const float*)d_in[3];
  const int T = out_size / 24769;   // 64*128 + 64 + 128*128 + 128 + 1
  float* out = (float*)d_out;
  float* ws = (float*)d_ws;

  hipLaunchKernelGGL(lqr_iter, dim3(1), dim3(TPB), 0, stream, F, f, C, c, out, ws, T);
  hipLaunchKernelGGL(lqr_fill, dim3(T), dim3(256), 0, stream, ws, out, T);
}